// Round 2
// baseline (129.938 us; speedup 1.0000x reference)
//
#include <hip/hip_runtime.h>
#include <stdint.h>

// NaiveBias (symmetric Toeplitz bias contraction): out[b,j,h,d] = sum_l w[h,|l-j|] * v[b,l,h,d]
// B=2, S=2048, H=16, D=64, fp32 in/out.
// Strategy: per (b,h), C(2048x64) = T(2048x2048, Toeplitz from w) @ V(2048x64) via
// mfma_f32_16x16x32_bf16 with 3-term bf16 hi/lo split for fp32-grade accuracy.
// Budget: 51.5 GFLOP @ ~2075 TF => ~25 us MFMA floor; per-CU K-step LDS (437-755 cyc)
// sits under the MFMA budget (933 cyc/SIMD) => MFMA-bound by design.

#define SS 2048
#define HH 16
#define BB 2
#define DD 64
#define BHN 32

typedef uint32_t u32;
typedef uint16_t u16;
typedef __attribute__((ext_vector_type(8))) short bf16x8;
typedef __attribute__((ext_vector_type(4))) float f32x4;

__device__ __forceinline__ u16 f2bf(float x) {
  u32 u = __float_as_uint(x);
  u = u + 0x7fffu + ((u >> 16) & 1u);   // RNE truncate to bf16
  return (u16)(u >> 16);
}
__device__ __forceinline__ float bf2f(u16 h) {
  return __uint_as_float(((u32)h) << 16);
}
__device__ __forceinline__ void bfsplit(float x, u16& hi, u16& lo) {
  hi = f2bf(x);
  lo = f2bf(x - bf2f(hi));   // residual; x = hi + lo + O(2^-18 |x|)
}

// ---------------- pre-pass 1: v -> transposed bf16 hi/lo  vht[bh][d][l] ----------------
__global__ __launch_bounds__(256) void prep_v(const float* __restrict__ v,
                                              u16* __restrict__ vhi, u16* __restrict__ vlo)
{
  __shared__ float tile[64][68];          // 64 l x 64 d, pad to 68 for column reads
  const int t = threadIdx.x;
  const int l0 = blockIdx.x * 64;
  const int bh = blockIdx.y;
  const int b = bh >> 4, h = bh & 15;
  {
    const int lr = t >> 2, ds = (t & 3) * 16;
    const float* src = v + (((size_t)b * SS + l0 + lr) * HH + h) * DD + ds;
    float4 r0 = *(const float4*)(src + 0);
    float4 r1 = *(const float4*)(src + 4);
    float4 r2 = *(const float4*)(src + 8);
    float4 r3 = *(const float4*)(src + 12);
    *(float4*)&tile[lr][ds + 0]  = r0;
    *(float4*)&tile[lr][ds + 4]  = r1;
    *(float4*)&tile[lr][ds + 8]  = r2;
    *(float4*)&tile[lr][ds + 12] = r3;
  }
  __syncthreads();
  {
    const int d = t >> 2, lc = t & 3;
    union { u16 s[16]; uint4 q[2]; } ph, pl;
    #pragma unroll
    for (int i = 0; i < 16; ++i) {
      float x = tile[lc * 16 + i][d];
      u16 hi, lo; bfsplit(x, hi, lo);
      ph.s[i] = hi; pl.s[i] = lo;
    }
    u16* dh = vhi + (size_t)bh * (DD * SS) + (size_t)d * SS + l0 + lc * 16;
    u16* dl = vlo + (size_t)bh * (DD * SS) + (size_t)d * SS + l0 + lc * 16;
    *(uint4*)(dh + 0) = ph.q[0];
    *(uint4*)(dh + 8) = ph.q[1];
    *(uint4*)(dl + 0) = pl.q[0];
    *(uint4*)(dl + 8) = pl.q[1];
  }
}

// ---------------- pre-pass 2: packed Toeplitz table  upk[h][t] = {hi,lo}(w[h][|2047-t|]) ----------------
__global__ __launch_bounds__(256) void prep_w(const float* __restrict__ w, u32* __restrict__ upk)
{
  const int h = blockIdx.x;
  const int t = blockIdx.y * 256 + threadIdx.x;   // 0..4095
  int r = 2047 - t;
  int idx = r < 0 ? -r : r;
  if (idx > 2047) idx = 2047;                     // t=4095 unused
  float x = w[h * SS + idx];
  u16 hi, lo; bfsplit(x, hi, lo);
  upk[h * 4096 + t] = (u32)hi | ((u32)lo << 16);
}

// unpack 8 packed dwords -> hi/lo bf16x8 fragments
__device__ __forceinline__ void load_afrag(const u32* tab, int t0, bf16x8& hi, bf16x8& lo) {
  u32 d0 = tab[t0 + 0], d1 = tab[t0 + 1], d2 = tab[t0 + 2], d3 = tab[t0 + 3];
  u32 d4 = tab[t0 + 4], d5 = tab[t0 + 5], d6 = tab[t0 + 6], d7 = tab[t0 + 7];
  union { u32 u[4]; bf16x8 v; } H, L;
  H.u[0] = __builtin_amdgcn_perm(d1, d0, 0x05040100u);  // lo16 halves -> hi frag
  H.u[1] = __builtin_amdgcn_perm(d3, d2, 0x05040100u);
  H.u[2] = __builtin_amdgcn_perm(d5, d4, 0x05040100u);
  H.u[3] = __builtin_amdgcn_perm(d7, d6, 0x05040100u);
  L.u[0] = __builtin_amdgcn_perm(d1, d0, 0x07060302u);  // hi16 halves -> lo frag
  L.u[1] = __builtin_amdgcn_perm(d3, d2, 0x07060302u);
  L.u[2] = __builtin_amdgcn_perm(d5, d4, 0x07060302u);
  L.u[3] = __builtin_amdgcn_perm(d7, d6, 0x07060302u);
  hi = H.v; lo = L.v;
}

// ---------------- main: per (b,h) Toeplitz GEMM ----------------
__global__ __launch_bounds__(256) void toeplitz_mm(
    const u16* __restrict__ vhi, const u16* __restrict__ vlo,
    const u32* __restrict__ upk, float* __restrict__ out)
{
  __shared__ __align__(16) u32 tab[4096];          // packed (hi,lo) Toeplitz table, 16 KB
  __shared__ __align__(16) u16 vt[2][2][64][32];   // [dbuf][hi/lo][d][l-tile], 16 KB

  const int tid = threadIdx.x;
  const int lane = tid & 63;
  const int wv = tid >> 6;        // wave 0..3, owns 64 j-rows
  const int m = lane & 15;        // MFMA row/col within fragment
  const int g = lane >> 4;        // MFMA k-group

  // XCD-aware swizzle (bijective, 256 blocks / 8 XCDs): give each XCD 4 bh-panels
  // (2 MB vhi+vlo < 4 MiB L2) instead of scattering all 32 panels across XCDs.
  const int lin = blockIdx.x + 8 * blockIdx.y;   // dispatch-linear id; XCD = lin & 7
  const int xcd = lin & 7;
  const int sl  = lin >> 3;                      // 0..31 within XCD
  const int bh  = (xcd << 2) | (sl >> 3);        // 4 consecutive panels per XCD
  const int jt  = sl & 7;                        // j-tile 0..7 (256 rows each)
  const int b = bh >> 4, h = bh & 15;

  // stage Toeplitz table to LDS
  {
    const u32* src = upk + h * 4096;
    #pragma unroll
    for (int r = 0; r < 4; ++r) {
      int idx = r * 1024 + tid * 4;
      *(uint4*)&tab[idx] = *(const uint4*)&src[idx];
    }
  }

  // V staging geometry: thread -> (d row, 16B granule), XOR-swizzled granule slot
  const int sd = tid >> 2;
  const int sg = tid & 3;
  const int sswz = (sd & 3) ^ ((sd >> 2) & 3);
  const int sp = sg ^ sswz;
  const u16* gvh = vhi + (size_t)bh * (DD * SS) + (size_t)sd * SS + sg * 8;
  const u16* gvl = vlo + (size_t)bh * (DD * SS) + (size_t)sd * SS + sg * 8;

  // B-fragment per-lane read offset (elements), same swizzle
  const int bswz = (m & 3) ^ ((m >> 2) & 3);
  const int boff = m * 32 + ((g ^ bswz) << 3);

  // A (Toeplitz) base index: t = 2047 - j + l, per-lane constant part
  const int jb = jt * 256 + wv * 64;
  const int tA = 2047 - jb - m + 8 * g;

  // stage tile 0
  {
    uint4 th = *(const uint4*)(gvh);
    uint4 tl = *(const uint4*)(gvl);
    *(uint4*)&vt[0][0][sd][sp * 8] = th;
    *(uint4*)&vt[0][1][sd][sp * 8] = tl;
  }
  __syncthreads();

  bf16x8 Ahi[4], Alo[4];
  #pragma unroll
  for (int jf = 0; jf < 4; ++jf)
    load_afrag(tab, tA - 16 * jf, Ahi[jf], Alo[jf]);

  f32x4 acc[4][4];
  #pragma unroll
  for (int i = 0; i < 4; ++i)
    #pragma unroll
    for (int j = 0; j < 4; ++j)
      acc[i][j] = (f32x4)(0.0f);

  int buf = 0;
  for (int s = 0; s < 64; ++s) {
    const int s1 = (s + 1) & 63;
    // issue next-tile global loads early (hidden under MFMA)
    uint4 th = *(const uint4*)(gvh + s1 * 32);
    uint4 tl = *(const uint4*)(gvl + s1 * 32);

    const u16* vbh = &vt[buf][0][0][0];
    const u16* vbl = &vt[buf][1][0][0];
    #pragma unroll
    for (int nf = 0; nf < 4; ++nf) {
      bf16x8 bhf = *(const bf16x8*)(vbh + nf * 512 + boff);
      bf16x8 blf = *(const bf16x8*)(vbl + nf * 512 + boff);
      #pragma unroll
      for (int jf = 0; jf < 4; ++jf) {
        acc[jf][nf] = __builtin_amdgcn_mfma_f32_16x16x32_bf16(Ahi[jf], bhf, acc[jf][nf], 0, 0, 0);
        acc[jf][nf] = __builtin_amdgcn_mfma_f32_16x16x32_bf16(Ahi[jf], blf, acc[jf][nf], 0, 0, 0);
        acc[jf][nf] = __builtin_amdgcn_mfma_f32_16x16x32_bf16(Alo[jf], bhf, acc[jf][nf], 0, 0, 0);
      }
    }

    // Toeplitz shift-reuse: frag(jf,s+1) = frag(jf-2,s); only jf=0,1 fresh
    bf16x8 n0h, n0l, n1h, n1l;
    load_afrag(tab, tA + 32 * s1,      n0h, n0l);
    load_afrag(tab, tA + 32 * s1 - 16, n1h, n1l);
    Ahi[3] = Ahi[1]; Alo[3] = Alo[1];
    Ahi[2] = Ahi[0]; Alo[2] = Alo[0];
    Ahi[0] = n0h;    Alo[0] = n0l;
    Ahi[1] = n1h;    Alo[1] = n1l;

    // write next tile into the other buffer (its readers all passed last barrier)
    *(uint4*)&vt[buf ^ 1][0][sd][sp * 8] = th;
    *(uint4*)&vt[buf ^ 1][1][sd][sp * 8] = tl;
    __syncthreads();
    buf ^= 1;
  }

  // epilogue: C/D layout col=lane&15, row=(lane>>4)*4+q
  #pragma unroll
  for (int jf = 0; jf < 4; ++jf) {
    #pragma unroll
    for (int nf = 0; nf < 4; ++nf) {
      f32x4 c = acc[jf][nf];
      #pragma unroll
      for (int q = 0; q < 4; ++q) {
        int j = jb + jf * 16 + g * 4 + q;
        int d = nf * 16 + m;
        out[(((size_t)b * SS + j) * HH + h) * DD + d] = c[q];
      }
    }
  }
}

// ---------------- fallback (tiny ws): direct fp32 VALU, correct but slow ----------------
__global__ __launch_bounds__(256) void fallback_k(const float* __restrict__ v,
                                                  const float* __restrict__ w,
                                                  float* __restrict__ out)
{
  __shared__ float wrow[SS];
  const int t = threadIdx.x;
  const int j0 = blockIdx.x * 64;
  const int bh = blockIdx.y;
  const int b = bh >> 4, h = bh & 15;
  for (int i = t; i < SS; i += 256) wrow[i] = w[h * SS + i];
  __syncthreads();
  const int jj = t >> 6, d = t & 63;
  float acc[16];
  #pragma unroll
  for (int r = 0; r < 16; ++r) acc[r] = 0.f;
  for (int l = 0; l < SS; ++l) {
    float vv = v[(((size_t)b * SS + l) * HH + h) * DD + d];
    #pragma unroll
    for (int r = 0; r < 16; ++r) {
      int dj = l - (j0 + jj * 16 + r);
      acc[r] += wrow[dj < 0 ? -dj : dj] * vv;
    }
  }
  #pragma unroll
  for (int r = 0; r < 16; ++r)
    out[(((size_t)b * SS + (j0 + jj * 16 + r)) * HH + h) * DD + d] = acc[r];
}

extern "C" void kernel_launch(void* const* d_in, const int* in_sizes, int n_in,
                              void* d_out, int out_size, void* d_ws, size_t ws_size,
                              hipStream_t stream)
{
  const float* v = (const float*)d_in[0];
  const float* w = (const float*)d_in[1];
  float* out = (float*)d_out;
  const size_t vh_elems = (size_t)BHN * DD * SS;               // 4,194,304
  const size_t need = vh_elems * 4 + (size_t)HH * 4096 * 4;    // 16 MB + 256 KB
  if (ws_size >= need) {
    u16* vhi = (u16*)d_ws;
    u16* vlo = vhi + vh_elems;
    u32* upk = (u32*)((char*)d_ws + vh_elems * 4);
    prep_v<<<dim3(32, 32), 256, 0, stream>>>(v, vhi, vlo);
    prep_w<<<dim3(16, 16), 256, 0, stream>>>(w, upk);
    toeplitz_mm<<<dim3(8, 32), 256, 0, stream>>>(vhi, vlo, upk, out);
  } else {
    fallback_k<<<dim3(32, 32), 256, 0, stream>>>(v, w, out);
  }
}

// Round 3
// 113.406 us; speedup vs baseline: 1.1458x; 1.1458x over previous
//
#include <hip/hip_runtime.h>
#include <stdint.h>

// NaiveBias (symmetric Toeplitz bias contraction): out[b,j,h,d] = sum_l w[h,|l-j|] * v[b,l,h,d]
// B=2, S=2048, H=16, D=64, fp32 in/out.
// R3: fused single GEMM kernel (prep_v eliminated), 8-wave K-split blocks for 2 waves/SIMD.
// Per (b,h): C(2048x64) = T(2048x2048 Toeplitz) @ V(2048x64), mfma_f32_16x16x32_bf16,
// 3-term bf16 hi/lo split (Thi*Vhi + Thi*Vlo + Tlo*Vhi) for fp32-grade accuracy.

#define SS 2048
#define HH 16
#define DD 64

typedef uint32_t u32;
typedef uint16_t u16;
typedef __attribute__((ext_vector_type(8))) short bf16x8;
typedef __attribute__((ext_vector_type(4))) float f32x4;

__device__ __forceinline__ u16 f2bf(float x) {
  u32 u = __float_as_uint(x);
  u = u + 0x7fffu + ((u >> 16) & 1u);   // RNE truncate to bf16
  return (u16)(u >> 16);
}
__device__ __forceinline__ float bf2f(u16 h) {
  return __uint_as_float(((u32)h) << 16);
}
__device__ __forceinline__ void bfsplit(float x, u16& hi, u16& lo) {
  hi = f2bf(x);
  lo = f2bf(x - bf2f(hi));   // exact residual; x = hi + lo + O(2^-16 |x|)
}

// ---------------- pre-pass: packed Toeplitz table  upk[h][t] = {hi,lo}(w[h][|2047-t|]) ----------------
__global__ __launch_bounds__(256) void prep_w(const float* __restrict__ w, u32* __restrict__ upk)
{
  const int h = blockIdx.x;
  const int t = blockIdx.y * 256 + threadIdx.x;   // 0..4095
  int r = 2047 - t;
  int idx = r < 0 ? -r : r;
  if (idx > 2047) idx = 2047;                     // t=4095 unused
  float x = w[h * SS + idx];
  u16 hi, lo; bfsplit(x, hi, lo);
  upk[h * 4096 + t] = (u32)hi | ((u32)lo << 16);
}

// unpack 8 packed dwords -> hi/lo bf16x8 fragments
__device__ __forceinline__ void load_afrag(const u32* tab, int t0, bf16x8& hi, bf16x8& lo) {
  u32 d0 = tab[t0 + 0], d1 = tab[t0 + 1], d2 = tab[t0 + 2], d3 = tab[t0 + 3];
  u32 d4 = tab[t0 + 4], d5 = tab[t0 + 5], d6 = tab[t0 + 6], d7 = tab[t0 + 7];
  union { u32 u[4]; bf16x8 v; } H, L;
  H.u[0] = __builtin_amdgcn_perm(d1, d0, 0x05040100u);  // lo16 halves -> hi frag
  H.u[1] = __builtin_amdgcn_perm(d3, d2, 0x05040100u);
  H.u[2] = __builtin_amdgcn_perm(d5, d4, 0x05040100u);
  H.u[3] = __builtin_amdgcn_perm(d7, d6, 0x05040100u);
  L.u[0] = __builtin_amdgcn_perm(d1, d0, 0x07060302u);  // hi16 halves -> lo frag
  L.u[1] = __builtin_amdgcn_perm(d3, d2, 0x07060302u);
  L.u[2] = __builtin_amdgcn_perm(d5, d4, 0x07060302u);
  L.u[3] = __builtin_amdgcn_perm(d7, d6, 0x07060302u);
  hi = H.v; lo = L.v;
}

// ---------------- fused main: per (b,h) Toeplitz GEMM, 8 waves, K-split halves ----------------
__global__ __launch_bounds__(512, 2) void toeplitz_fused(
    const float* __restrict__ v, const u32* __restrict__ upk, float* __restrict__ out)
{
  __shared__ __align__(16) u32 tab[4096];               // 16 KB packed Toeplitz table
  __shared__ __align__(16) u16 vt[2][2][2][64][32];     // [khalf][dbuf][hi/lo][d][l] 32 KB
  __shared__ __align__(16) float red[2][64][16];        // 8 KB cross-half reduction

  const int tid  = threadIdx.x;
  const int lane = tid & 63;
  const int wv   = tid >> 6;        // 0..7
  const int half = wv >> 2;         // K-half: l in [half*1024, half*1024+1024)
  const int oct  = wv & 3;          // j-subtile index AND staging l-octet
  const int m    = lane & 15;       // MFMA row/col within fragment
  const int g    = lane >> 4;       // MFMA k-group

  // XCD-aware bijective swizzle: 4 (b,h) panels per XCD (2 MB fp32 < 4 MiB L2)
  const int lin = blockIdx.x;       // 0..255
  const int xcd = lin & 7;
  const int sl  = lin >> 3;         // 0..31
  const int bh  = (xcd << 2) | (sl >> 3);
  const int jt  = sl & 7;           // j-tile (256 rows)
  const int b = bh >> 4, h = bh & 15;

  // stage Toeplitz table (barrier deferred to first loop iteration)
  {
    const u32* src = upk + h * 4096;
    *(uint4*)&tab[tid * 4]        = *(const uint4*)&src[tid * 4];
    *(uint4*)&tab[2048 + tid * 4] = *(const uint4*)&src[2048 + tid * 4];
  }

  // staging geometry: thread stages row d=lane, l-octet oct, of its own half
  const int sd = lane;
  const int sslot = oct ^ ((sd >> 2) & 3);              // bank-balanced granule slot
  u16* wb0 = &vt[half][0][0][sd][sslot * 8];
  u16* wb1 = &vt[half][1][0][sd][sslot * 8];
  const float* gsrc = v + (((size_t)b * SS + half * 1024 + oct * 8) * HH + h) * DD + sd;
  // l-stride in floats = HH*DD = 1024

  // B-frag read offset (u16 elems): row m (+16*nf), granule g with matching swizzle
  const int bro = m * 32 + ((g ^ ((m >> 2) & 3)) << 3);

  // A (Toeplitz) base: t = 2047 - j + l
  const int jb = jt * 256 + oct * 64;
  const int tA = 2047 - jb - m + 8 * g + half * 1024;

  // prologue: load tile s=0 into regs
  float r[8];
  #pragma unroll
  for (int i = 0; i < 8; ++i) r[i] = gsrc[i * 1024];

  bf16x8 Ahi[4], Alo[4];
  f32x4 acc[4][4];
  #pragma unroll
  for (int i = 0; i < 4; ++i)
    #pragma unroll
    for (int j = 0; j < 4; ++j)
      acc[i][j] = (f32x4)(0.0f);

  for (int s = 0; s < 32; ++s) {
    // split + LDS write of tile s
    u32 ph[4], pl[4];
    #pragma unroll
    for (int i = 0; i < 4; ++i) {
      u16 h0, l0, h1, l1;
      bfsplit(r[2 * i], h0, l0);
      bfsplit(r[2 * i + 1], h1, l1);
      ph[i] = (u32)h0 | ((u32)h1 << 16);
      pl[i] = (u32)l0 | ((u32)l1 << 16);
    }
    u16* wb = (s & 1) ? wb1 : wb0;
    *(uint4*)wb          = *(const uint4*)ph;
    *(uint4*)(wb + 2048) = *(const uint4*)pl;          // lo plane (+64*32 u16)
    __syncthreads();                                    // s=0: also covers tab staging

    // prefetch tile s+1 (in flight across the MFMA phase, consumed before next barrier)
    if (s < 31) {
      const float* gs = gsrc + (size_t)(s + 1) * 32 * 1024;
      #pragma unroll
      for (int i = 0; i < 8; ++i) r[i] = gs[i * 1024];
    }

    // A fragments: Toeplitz shift-reuse frag(jf,s) = frag(jf-2,s-1); 2 fresh pairs/iter
    if (s == 0) {
      #pragma unroll
      for (int jf = 0; jf < 4; ++jf)
        load_afrag(tab, tA - 16 * jf, Ahi[jf], Alo[jf]);
    } else {
      bf16x8 t0h = Ahi[0], t0l = Alo[0], t1h = Ahi[1], t1l = Alo[1];
      load_afrag(tab, tA + 32 * s,      Ahi[0], Alo[0]);
      load_afrag(tab, tA + 32 * s - 16, Ahi[1], Alo[1]);
      Ahi[2] = t0h; Alo[2] = t0l;
      Ahi[3] = t1h; Alo[3] = t1l;
    }

    // B fragments + MFMA (48/iter/wave)
    const u16* vb = &vt[half][s & 1][0][0][0];
    #pragma unroll
    for (int nf = 0; nf < 4; ++nf) {
      bf16x8 bhf = *(const bf16x8*)(vb + nf * 512 + bro);
      bf16x8 blf = *(const bf16x8*)(vb + 2048 + nf * 512 + bro);
      #pragma unroll
      for (int jf = 0; jf < 4; ++jf) {
        acc[jf][nf] = __builtin_amdgcn_mfma_f32_16x16x32_bf16(Ahi[jf], bhf, acc[jf][nf], 0, 0, 0);
        acc[jf][nf] = __builtin_amdgcn_mfma_f32_16x16x32_bf16(Ahi[jf], blf, acc[jf][nf], 0, 0, 0);
        acc[jf][nf] = __builtin_amdgcn_mfma_f32_16x16x32_bf16(Alo[jf], bhf, acc[jf][nf], 0, 0, 0);
      }
    }
    __syncthreads();   // tile s fully consumed before it can be overwritten at s+2
  }

  // cross-half reduction + store: wave w (half0) pairs with w+4 (half1), same jb.
  #pragma unroll
  for (int jf = 0; jf < 4; ++jf) {
    for (int p = 0; p < 2; ++p) {
      if (half == 1 && (oct >> 1) == p) {
        float* dst = &red[oct & 1][lane][0];
        #pragma unroll
        for (int nf = 0; nf < 4; ++nf)
          *(f32x4*)(dst + nf * 4) = acc[jf][nf];
      }
      __syncthreads();
      if (half == 0 && (oct >> 1) == p) {
        const float* sp = &red[oct & 1][lane][0];
        #pragma unroll
        for (int nf = 0; nf < 4; ++nf) {
          f32x4 c = acc[jf][nf] + *(const f32x4*)(sp + nf * 4);
          #pragma unroll
          for (int q = 0; q < 4; ++q) {
            int j = jb + jf * 16 + g * 4 + q;
            int d = nf * 16 + m;
            out[(((size_t)b * SS + j) * HH + h) * DD + d] = c[q];
          }
        }
      }
      __syncthreads();
    }
  }
}

// ---------------- fallback (tiny ws): direct fp32 VALU, correct but slow ----------------
__global__ __launch_bounds__(256) void fallback_k(const float* __restrict__ v,
                                                  const float* __restrict__ w,
                                                  float* __restrict__ out)
{
  __shared__ float wrow[SS];
  const int t = threadIdx.x;
  const int j0 = blockIdx.x * 64;
  const int bh = blockIdx.y;
  const int b = bh >> 4, h = bh & 15;
  for (int i = t; i < SS; i += 256) wrow[i] = w[h * SS + i];
  __syncthreads();
  const int jj = t >> 6, d = t & 63;
  float acc[16];
  #pragma unroll
  for (int r = 0; r < 16; ++r) acc[r] = 0.f;
  for (int l = 0; l < SS; ++l) {
    float vv = v[(((size_t)b * SS + l) * HH + h) * DD + d];
    #pragma unroll
    for (int r = 0; r < 16; ++r) {
      int dj = l - (j0 + jj * 16 + r);
      acc[r] += wrow[dj < 0 ? -dj : dj] * vv;
    }
  }
  #pragma unroll
  for (int r = 0; r < 16; ++r)
    out[(((size_t)b * SS + (j0 + jj * 16 + r)) * HH + h) * DD + d] = acc[r];
}

extern "C" void kernel_launch(void* const* d_in, const int* in_sizes, int n_in,
                              void* d_out, int out_size, void* d_ws, size_t ws_size,
                              hipStream_t stream)
{
  const float* v = (const float*)d_in[0];
  const float* w = (const float*)d_in[1];
  float* out = (float*)d_out;
  const size_t need = (size_t)HH * 4096 * 4;   // 256 KB packed Toeplitz table
  if (ws_size >= need) {
    u32* upk = (u32*)d_ws;
    prep_w<<<dim3(16, 16), 256, 0, stream>>>(w, upk);
    toeplitz_fused<<<dim3(256), 512, 0, stream>>>(v, upk, out);
  } else {
    fallback_k<<<dim3(32, 32), 256, 0, stream>>>(v, w, out);
  }
}